// Round 11
// baseline (109.731 us; speedup 1.0000x reference)
//
#include <hip/hip_runtime.h>
#include <hip/hip_bf16.h>

typedef __attribute__((ext_vector_type(8))) short short8;
typedef __attribute__((ext_vector_type(4))) float f32x4;
typedef __attribute__((ext_vector_type(16))) float f32x16;
typedef __attribute__((ext_vector_type(4))) unsigned int uint4v;
typedef __attribute__((ext_vector_type(4))) unsigned short ushort4v;

#define DEV static __device__ __forceinline__

DEV unsigned short f2bf(float f){
  unsigned u = __float_as_uint(f);
  u += 0x7fffu + ((u >> 16) & 1u);
  return (unsigned short)(u >> 16);
}

DEV float bf2f(unsigned short h){
  unsigned u = ((unsigned)h) << 16;
  float f;
  __builtin_memcpy(&f, &u, 4);
  return f;
}

DEV unsigned pack2bf(float a, float b){
  __hip_bfloat162 h = __float22bfloat162_rn(make_float2(a, b));
  unsigned u;
  __builtin_memcpy(&u, &h, 4);
  return u;
}

// B=2, C=64, H=W=64 -> S=4096, NH=4, HD=16, GROUPS=32
#define QSCALE 0.180336880111f   // 0.125 * log2(e); softmax in exp2 domain, max-free
#define NSPLIT 8
#define NT 8                     // KV tiles (of 64) per split chunk (512 rows)
#define REP 4                    // MEASUREMENT: amplify attn compute 4x (O and lsum
                                 // both scale 4x -> normalized output identical)

// ---------------- K1: GroupNorm partial sums (512 blocks = 64 groups x 8) ----------------
__global__ __launch_bounds__(256) void gn_partial_k(const float* __restrict__ x,
                                                    float* __restrict__ gp){
  int blk = blockIdx.x;
  float4 v = ((const float4*)(x + (size_t)blk*1024))[threadIdx.x];
  float s = v.x+v.y+v.z+v.w;
  float q = v.x*v.x+v.y*v.y+v.z*v.z+v.w*v.w;
  #pragma unroll
  for (int off = 1; off < 64; off <<= 1){
    s += __shfl_xor(s, off);
    q += __shfl_xor(q, off);
  }
  __shared__ float red[8];
  int w = threadIdx.x >> 6;
  if ((threadIdx.x & 63) == 0){ red[w*2] = s; red[w*2+1] = q; }
  __syncthreads();
  if (threadIdx.x == 0){
    gp[blk*2+0] = red[0]+red[2]+red[4]+red[6];
    gp[blk*2+1] = red[1]+red[3]+red[5]+red[7];
  }
}

// ---------------- K2: GN finalize + GN-apply + QKV 1x1 conv -> bf16 ----------------
// q,k: [bn][s][d=16] (q pre-scaled by QSCALE).
// vt : [bn][d=16][s=4096] transposed V, sigma (s bits 2<->3 swap) applied to s.
// grid 512 = b(2) x s-tile(256 of 16)
__global__ __launch_bounds__(256) void qkv_k(const float* __restrict__ x,
    const float* __restrict__ gp, const float* __restrict__ gsc,
    const float* __restrict__ gbi, const float* __restrict__ wq,
    unsigned short* __restrict__ q, unsigned short* __restrict__ k,
    unsigned short* __restrict__ vt){
  int b  = blockIdx.x >> 8;
  int s0 = (blockIdx.x & 255) * 16;
  __shared__ float W[192][68];    // padded: bank-conflict-free o-reads
  __shared__ float A[16][68];     // [s_local][c]
  __shared__ float MS[32][2];     // per-group mean, rstd
  int t = threadIdx.x;
  for (int i = t; i < 3072; i += 256){
    int o = i >> 4, c4 = (i & 15) * 4;
    *(float4*)&W[o][c4] = ((const float4*)wq)[i];
  }
  if (t < 32){
    float s = 0.f, ss = 0.f;
    #pragma unroll
    for (int i = 0; i < 8; ++i){
      const float* pp = gp + ((b*32 + t)*8 + i)*2;
      s += pp[0]; ss += pp[1];
    }
    float mean = s * (1.f/8192.f);
    MS[t][0] = mean;
    MS[t][1] = rsqrtf(ss * (1.f/8192.f) - mean*mean + 1e-5f);
  }
  __syncthreads();
  {
    int c  = t >> 2;
    int s4 = (t & 3) * 4;
    const float* px = x + ((size_t)b*64 + c)*4096 + s0 + s4;
    float4 v0 = *(const float4*)px;
    float sc = gsc[c] * MS[c>>1][1];
    float bi = gbi[c] - MS[c>>1][0] * sc;
    A[s4+0][c]=v0.x*sc+bi; A[s4+1][c]=v0.y*sc+bi;
    A[s4+2][c]=v0.z*sc+bi; A[s4+3][c]=v0.w*sc+bi;
  }
  __syncthreads();
  int sl = t >> 4, grp = t & 15;
  float acc[12];
  #pragma unroll
  for (int j = 0; j < 12; ++j) acc[j] = 0.f;
  for (int c4 = 0; c4 < 16; ++c4){
    float4 a = *(const float4*)&A[sl][c4*4];
    #pragma unroll
    for (int j = 0; j < 12; ++j){
      float4 wv = *(const float4*)&W[grp + j*16][c4*4];
      acc[j] = fmaf(a.x, wv.x, fmaf(a.y, wv.y, fmaf(a.z, wv.z, fmaf(a.w, wv.w, acc[j]))));
    }
  }
  int s = s0 + sl;
  // sigma(sl): swap bits 2 and 3 (matches attn PV A-frag register order)
  int slp = (sl & 0x3) | (((sl >> 2) & 1) << 3) | (((sl >> 3) & 1) << 2);
  #pragma unroll
  for (int j = 0; j < 12; ++j){
    int o = grp + j*16;
    int n = o / 48, r = o % 48;
    float val = acc[j];
    if (r < 16){
      q[(((size_t)b*4 + n)*4096 + s)*16 + r] = f2bf(val * QSCALE);
    } else if (r < 32){
      k[(((size_t)b*4 + n)*4096 + s)*16 + r - 16] = f2bf(val);
    } else {
      vt[((size_t)(b*4 + n)*16 + (r - 32))*4096 + s0 + slp] = f2bf(val);
    }
  }
}

// ---------------- K3: flash attention — MEASUREMENT ROUND: REP x4 ----------------
// Identical structure to round 10 (software-pipelined tile loop), but the whole
// compute body repeats REP times. O0/O1/lsum accumulate across reps (output is
// normalized by lsum in oproj, so the 4x scale cancels exactly). An opaque zero
// 'ofs' feeds every load address per rep so the compiler cannot CSE reps away.
// Purpose: lift attn_k above the 40us fill ceiling -> real counters; dur/REP =
// true attn cost; scaling factor vs inferred baseline = compute- vs latency-bound.
__global__ __launch_bounds__(256, 4) void attn_k(const unsigned short* __restrict__ qb,
    const unsigned short* __restrict__ kb, const unsigned short* __restrict__ vt,
    unsigned short* __restrict__ part, float* __restrict__ lsums){
  int blk = blockIdx.x;
  int bn = blk & 7;
  int sp = (blk >> 3) & (NSPLIT - 1);
  int qg = blk >> 6;                      // 0..31
  int t = threadIdx.x, w = t >> 6, l = t & 63;
  int lq = l & 31, hi = l >> 5;

  __shared__ unsigned short Klds[8192];   // [kv=512][d=16]  16 KB

  {  // stage K chunk (linear; dense contiguous reads later)
    const unsigned short* ksrc = kb + ((size_t)bn*4096 + sp*512)*16;
    #pragma unroll
    for (int p = 0; p < 4; ++p){
      int G = p*256 + t;
      *(short8*)&Klds[G*8] = *(const short8*)(ksrc + (size_t)G*8);
    }
  }

  int qrow = qg*128 + w*32;
  short8 qf = *(const short8*)(qb + ((size_t)bn*4096 + qrow)*16 + (size_t)lq*16 + hi*8);

  const unsigned short* vaddr0 = vt + ((size_t)bn*16 + (lq & 15))*4096 + sp*512 + hi*8;
  bool vld = (lq < 16);

  short8 vsel;      // B-frag for lanes lq>=16: ones at col 16 (lsum), zero elsewhere
  {
    unsigned short c = (lq == 16) ? (unsigned short)0x3F80 : (unsigned short)0;
    #pragma unroll
    for (int r = 0; r < 8; ++r) vsel[r] = (short)c;
  }

  f32x16 O0, O1, zero;
  #pragma unroll
  for (int r = 0; r < 16; ++r){ O0[r] = 0.f; O1[r] = 0.f; zero[r] = 0.f; }

  __syncthreads();                        // K staged; only barrier in the kernel

  auto packP = [&](const f32x16& pc, int h8) -> short8 {
    uint4v pw;
    pw[0] = pack2bf(pc[h8+0], pc[h8+1]);
    pw[1] = pack2bf(pc[h8+2], pc[h8+3]);
    pw[2] = pack2bf(pc[h8+4], pc[h8+5]);
    pw[3] = pack2bf(pc[h8+6], pc[h8+7]);
    return __builtin_bit_cast(short8, pw);
  };

  #pragma unroll 1
  for (int rep = 0; rep < REP; ++rep){
    int ofs = 0;
    asm volatile("" : "+v"(ofs));         // opaque zero: defeats cross-rep CSE
    const unsigned short* vaddr = vaddr0 + ofs;

    // ---- prologue: QK(0), exp2, pack; preload K(1), V(0) ----
    short8 kf0 = *(const short8*)&Klds[(size_t)(lq*16 + hi*8 + ofs)];
    short8 kf1 = *(const short8*)&Klds[(size_t)((32 + lq)*16 + hi*8 + ofs)];
    f32x16 sA = __builtin_amdgcn_mfma_f32_32x32x16_bf16(kf0, qf, zero, 0, 0, 0);
    f32x16 sB = __builtin_amdgcn_mfma_f32_32x32x16_bf16(kf1, qf, zero, 0, 0, 0);
    kf0 = *(const short8*)&Klds[(size_t)((64 + lq)*16 + hi*8 + ofs)];
    kf1 = *(const short8*)&Klds[(size_t)((96 + lq)*16 + hi*8 + ofs)];
    short8 v0 = vsel, v1 = vsel, v2 = vsel, v3 = vsel;
    if (vld){
      v0 = *(const short8*)(vaddr);
      v1 = *(const short8*)(vaddr + 16);
      v2 = *(const short8*)(vaddr + 32);
      v3 = *(const short8*)(vaddr + 48);
    }
    #pragma unroll
    for (int r = 0; r < 16; ++r) sA[r] = __builtin_amdgcn_exp2f(sA[r]);
    #pragma unroll
    for (int r = 0; r < 16; ++r) sB[r] = __builtin_amdgcn_exp2f(sB[r]);
    short8 paA0 = packP(sA, 0), paA1 = packP(sA, 8);
    short8 paB0 = packP(sB, 0), paB1 = packP(sB, 8);

    // ---- steady state ----
    #pragma unroll 1
    for (int kt = 0; kt < NT-1; ++kt){
      __builtin_amdgcn_s_setprio(1);
      f32x16 nA = __builtin_amdgcn_mfma_f32_32x32x16_bf16(kf0, qf, zero, 0, 0, 0);
      f32x16 nB = __builtin_amdgcn_mfma_f32_32x32x16_bf16(kf1, qf, zero, 0, 0, 0);
      O0 = __builtin_amdgcn_mfma_f32_32x32x16_bf16(paA0, v0, O0, 0, 0, 0);
      O1 = __builtin_amdgcn_mfma_f32_32x32x16_bf16(paA1, v1, O1, 0, 0, 0);
      O0 = __builtin_amdgcn_mfma_f32_32x32x16_bf16(paB0, v2, O0, 0, 0, 0);
      O1 = __builtin_amdgcn_mfma_f32_32x32x16_bf16(paB1, v3, O1, 0, 0, 0);
      __builtin_amdgcn_s_setprio(0);
      if (kt + 2 < NT){
        kf0 = *(const short8*)&Klds[(size_t)(((kt+2)*64 + lq)*16 + hi*8 + ofs)];
        kf1 = *(const short8*)&Klds[(size_t)(((kt+2)*64 + 32 + lq)*16 + hi*8 + ofs)];
      }
      v0 = vsel; v1 = vsel; v2 = vsel; v3 = vsel;
      if (vld){
        const unsigned short* va = vaddr + (size_t)(kt+1)*64;
        v0 = *(const short8*)(va);
        v1 = *(const short8*)(va + 16);
        v2 = *(const short8*)(va + 32);
        v3 = *(const short8*)(va + 48);
      }
      #pragma unroll
      for (int r = 0; r < 16; ++r) nA[r] = __builtin_amdgcn_exp2f(nA[r]);
      #pragma unroll
      for (int r = 0; r < 16; ++r) nB[r] = __builtin_amdgcn_exp2f(nB[r]);
      paA0 = packP(nA, 0); paA1 = packP(nA, 8);
      paB0 = packP(nB, 0); paB1 = packP(nB, 8);
    }

    // ---- epilogue: PV(NT-1) ----
    __builtin_amdgcn_s_setprio(1);
    O0 = __builtin_amdgcn_mfma_f32_32x32x16_bf16(paA0, v0, O0, 0, 0, 0);
    O1 = __builtin_amdgcn_mfma_f32_32x32x16_bf16(paA1, v1, O1, 0, 0, 0);
    O0 = __builtin_amdgcn_mfma_f32_32x32x16_bf16(paB0, v2, O0, 0, 0, 0);
    O1 = __builtin_amdgcn_mfma_f32_32x32x16_bf16(paB1, v3, O1, 0, 0, 0);
    __builtin_amdgcn_s_setprio(0);
  }

  #pragma unroll
  for (int r = 0; r < 16; ++r) O0[r] += O1[r];

  // D[row=q][col]: col=lq (d for lq<16, lsum at col 16); row=(r&3)+8(r>>2)+4hi
  unsigned short* Op = part + (((size_t)sp*8 + bn)*4096 + qrow)*16;
  size_t lbase = ((size_t)sp*8 + bn)*4096 + qrow;
  #pragma unroll
  for (int r = 0; r < 16; ++r){
    int qr = (r&3) + 8*(r>>2) + 4*hi;
    if (lq < 16) __builtin_nontemporal_store(f2bf(O0[r]), &Op[(size_t)qr*16 + lq]);
  }
  if (lq == 16){
    #pragma unroll
    for (int r = 0; r < 16; ++r){
      int qr = (r&3) + 8*(r>>2) + 4*hi;
      __builtin_nontemporal_store(O0[r], &lsums[lbase + qr]);
    }
  }
}

// ---------------- K4: split-combine (bf16 parts) + out 1x1 conv + bias + residual ----------------
// grid 512 = b(2) x s-tile(256 of 16)
__global__ __launch_bounds__(256) void oproj_k(const unsigned short* __restrict__ part,
    const float* __restrict__ lsums, const float* __restrict__ wo,
    const float* __restrict__ bo, const float* __restrict__ x,
    float* __restrict__ out){
  int b  = blockIdx.x >> 8;
  int s0 = (blockIdx.x & 255) * 16;
  __shared__ float W[64][68];
  __shared__ float A[16][68];     // [s_local][c]
  int t = threadIdx.x;
  for (int i = t; i < 1024; i += 256){
    int o = i >> 4, c4 = (i & 15) * 4;
    *(float4*)&W[o][c4] = ((const float4*)wo)[i];
  }
  {
    int sl = t & 15;
    int u  = t >> 4;
    int n = u >> 2, d4 = (u & 3) * 4;
    size_t row = ((size_t)b*4 + n)*4096 + s0 + sl;
    float L = 0.f;
    #pragma unroll
    for (int sp = 0; sp < NSPLIT; ++sp)
      L += __builtin_nontemporal_load(&lsums[(size_t)sp*32768 + row]);
    f32x4 acc = {0.f,0.f,0.f,0.f};
    #pragma unroll
    for (int sp = 0; sp < NSPLIT; ++sp){
      ushort4v u0 = *(const ushort4v*)(part + ((size_t)sp*32768 + row)*16 + d4);
      acc[0] += bf2f(u0[0]); acc[1] += bf2f(u0[1]);
      acc[2] += bf2f(u0[2]); acc[3] += bf2f(u0[3]);
    }
    float inv = 1.f / L;
    A[sl][n*16+d4+0] = acc[0]*inv; A[sl][n*16+d4+1] = acc[1]*inv;
    A[sl][n*16+d4+2] = acc[2]*inv; A[sl][n*16+d4+3] = acc[3]*inv;
  }
  __syncthreads();
  int sl = t & 15, grp = t >> 4;
  float acc[4] = {0.f,0.f,0.f,0.f};
  for (int c4 = 0; c4 < 16; ++c4){
    float4 a = *(const float4*)&A[sl][c4*4];
    #pragma unroll
    for (int j = 0; j < 4; ++j){
      float4 wv = *(const float4*)&W[grp + j*16][c4*4];
      acc[j] = fmaf(a.x, wv.x, fmaf(a.y, wv.y, fmaf(a.z, wv.z, fmaf(a.w, wv.w, acc[j]))));
    }
  }
  int s = s0 + sl;
  #pragma unroll
  for (int j = 0; j < 4; ++j){
    int o = grp + j*16;
    size_t idx = ((size_t)b*64 + o)*4096 + s;
    out[idx] = acc[j] + bo[o] + x[idx];
  }
}

extern "C" void kernel_launch(void* const* d_in, const int* in_sizes, int n_in,
                              void* d_out, int out_size, void* d_ws, size_t ws_size,
                              hipStream_t stream){
  const float* x   = (const float*)d_in[0];
  const float* gsc = (const float*)d_in[1];
  const float* gbi = (const float*)d_in[2];
  const float* wq  = (const float*)d_in[3];
  const float* wo  = (const float*)d_in[4];
  const float* bo  = (const float*)d_in[5];
  float* out = (float*)d_out;

  char* ws = (char*)d_ws;
  float* gp           = (float*)ws;                                 // 4 KB
  unsigned short* q   = (unsigned short*)(ws + 8192);               // 1 MB
  unsigned short* k   = (unsigned short*)(ws + 8192 + 1048576);     // 1 MB
  unsigned short* vt  = (unsigned short*)(ws + 8192 + 2097152);     // 1 MB (8bn x 16 x 4096)
  unsigned short* part= (unsigned short*)(ws + 8192 + 3145728);     // 8 MB bf16 (8sp)
  float* lsums        = (float*)(ws + 8192 + 3145728 + 8388608);    // 1 MB

  gn_partial_k<<<512,  256, 0, stream>>>(x, gp);
  qkv_k       <<<512,  256, 0, stream>>>(x, gp, gsc, gbi, wq, q, k, vt);
  attn_k      <<<2048, 256, 0, stream>>>(q, k, vt, part, lsums);
  oproj_k     <<<512,  256, 0, stream>>>(part, lsums, wo, bo, x, out);
}

// Round 12
// 54.928 us; speedup vs baseline: 1.9977x; 1.9977x over previous
//
#include <hip/hip_runtime.h>
#include <hip/hip_bf16.h>

typedef __attribute__((ext_vector_type(8))) short short8;
typedef __attribute__((ext_vector_type(4))) float f32x4;
typedef __attribute__((ext_vector_type(16))) float f32x16;
typedef __attribute__((ext_vector_type(4))) unsigned int uint4v;
typedef __attribute__((ext_vector_type(4))) unsigned short ushort4v;

#define DEV static __device__ __forceinline__

DEV unsigned short f2bf(float f){
  unsigned u = __float_as_uint(f);
  u += 0x7fffu + ((u >> 16) & 1u);
  return (unsigned short)(u >> 16);
}

DEV float bf2f(unsigned short h){
  unsigned u = ((unsigned)h) << 16;
  float f;
  __builtin_memcpy(&f, &u, 4);
  return f;
}

DEV unsigned pack2bf(float a, float b){
  __hip_bfloat162 h = __float22bfloat162_rn(make_float2(a, b));
  unsigned u;
  __builtin_memcpy(&u, &h, 4);
  return u;
}

// B=2, C=64, H=W=64 -> S=4096, NH=4, HD=16, GROUPS=32
#define QSCALE 0.180336880111f   // 0.125 * log2(e); softmax in exp2 domain, max-free
#define NSPLIT 8
#define NT 8                     // KV tiles (of 64) per split chunk (512 rows)
#define KSTRIDE 24               // Klds row stride in ushorts (48B): conflict-free b128

// ---------------- K1: GroupNorm partial sums (512 blocks = 64 groups x 8) ----------------
__global__ __launch_bounds__(256) void gn_partial_k(const float* __restrict__ x,
                                                    float* __restrict__ gp){
  int blk = blockIdx.x;
  float4 v = ((const float4*)(x + (size_t)blk*1024))[threadIdx.x];
  float s = v.x+v.y+v.z+v.w;
  float q = v.x*v.x+v.y*v.y+v.z*v.z+v.w*v.w;
  #pragma unroll
  for (int off = 1; off < 64; off <<= 1){
    s += __shfl_xor(s, off);
    q += __shfl_xor(q, off);
  }
  __shared__ float red[8];
  int w = threadIdx.x >> 6;
  if ((threadIdx.x & 63) == 0){ red[w*2] = s; red[w*2+1] = q; }
  __syncthreads();
  if (threadIdx.x == 0){
    gp[blk*2+0] = red[0]+red[2]+red[4]+red[6];
    gp[blk*2+1] = red[1]+red[3]+red[5]+red[7];
  }
}

// ---------------- K2: GN finalize + GN-apply + QKV 1x1 conv -> bf16 ----------------
// q,k: [bn][s][d=16] (q pre-scaled by QSCALE).
// vt : [bn][row=32][s=4096]; rows 0-15 = V^T (sigma s-bit2<->3 swap applied),
//      row 16 = constant bf16 1.0 (lsum column; attn lanes lq>=16 clamp here).
// grid 512 = b(2) x s-tile(256 of 16)
__global__ __launch_bounds__(256) void qkv_k(const float* __restrict__ x,
    const float* __restrict__ gp, const float* __restrict__ gsc,
    const float* __restrict__ gbi, const float* __restrict__ wq,
    unsigned short* __restrict__ q, unsigned short* __restrict__ k,
    unsigned short* __restrict__ vt){
  int b  = blockIdx.x >> 8;
  int s0 = (blockIdx.x & 255) * 16;
  __shared__ float W[192][68];    // padded: bank-conflict-free o-reads
  __shared__ float A[16][68];     // [s_local][c]
  __shared__ float MS[32][2];     // per-group mean, rstd
  int t = threadIdx.x;
  for (int i = t; i < 3072; i += 256){
    int o = i >> 4, c4 = (i & 15) * 4;
    *(float4*)&W[o][c4] = ((const float4*)wq)[i];
  }
  if (t < 32){
    float s = 0.f, ss = 0.f;
    #pragma unroll
    for (int i = 0; i < 8; ++i){
      const float* pp = gp + ((b*32 + t)*8 + i)*2;
      s += pp[0]; ss += pp[1];
    }
    float mean = s * (1.f/8192.f);
    MS[t][0] = mean;
    MS[t][1] = rsqrtf(ss * (1.f/8192.f) - mean*mean + 1e-5f);
  }
  // ones row (row 16) of vt for this block's s-range
  if (t < 64){
    int n = t >> 4, si = t & 15;
    vt[((size_t)(b*4 + n)*32 + 16)*4096 + s0 + si] = (unsigned short)0x3F80;
  }
  __syncthreads();
  {
    int c  = t >> 2;
    int s4 = (t & 3) * 4;
    const float* px = x + ((size_t)b*64 + c)*4096 + s0 + s4;
    float4 v0 = *(const float4*)px;
    float sc = gsc[c] * MS[c>>1][1];
    float bi = gbi[c] - MS[c>>1][0] * sc;
    A[s4+0][c]=v0.x*sc+bi; A[s4+1][c]=v0.y*sc+bi;
    A[s4+2][c]=v0.z*sc+bi; A[s4+3][c]=v0.w*sc+bi;
  }
  __syncthreads();
  int sl = t >> 4, grp = t & 15;
  float acc[12];
  #pragma unroll
  for (int j = 0; j < 12; ++j) acc[j] = 0.f;
  for (int c4 = 0; c4 < 16; ++c4){
    float4 a = *(const float4*)&A[sl][c4*4];
    #pragma unroll
    for (int j = 0; j < 12; ++j){
      float4 wv = *(const float4*)&W[grp + j*16][c4*4];
      acc[j] = fmaf(a.x, wv.x, fmaf(a.y, wv.y, fmaf(a.z, wv.z, fmaf(a.w, wv.w, acc[j]))));
    }
  }
  int s = s0 + sl;
  // sigma(sl): swap bits 2 and 3 (matches attn PV A-frag register order)
  int slp = (sl & 0x3) | (((sl >> 2) & 1) << 3) | (((sl >> 3) & 1) << 2);
  #pragma unroll
  for (int j = 0; j < 12; ++j){
    int o = grp + j*16;
    int n = o / 48, r = o % 48;
    float val = acc[j];
    if (r < 16){
      q[(((size_t)b*4 + n)*4096 + s)*16 + r] = f2bf(val * QSCALE);
    } else if (r < 32){
      k[(((size_t)b*4 + n)*4096 + s)*16 + r - 16] = f2bf(val);
    } else {
      vt[((size_t)(b*4 + n)*32 + (r - 32))*4096 + s0 + slp] = f2bf(val);
    }
  }
}

// ---------------- K3: flash attention — instruction-diet version ----------------
// grid 2048 = qg(32) x sp(8) x bn(8), bn = blk&7 (XCD-local K/V working set).
// 4 waves/block; wave w owns q rows qg*128+w*32..+31.
// Changes vs r10 (driven by r11 counters: VALU 73%, 2.1M LDS conflicts):
//  - Klds row stride 48B -> ds_read_b128 conflict-free (was 4-way at 32B stride)
//  - V loads unconditional: lanes lq>=16 clamp to vt ones-row 16 (kills 16
//    v_cndmask + exec masking per tile)
//  - full unroll of the 8-tile loop: K/V offsets become immediates, no register
//    rotation movs, compiler pipelines across tiles (deeper V prefetch)
__global__ __launch_bounds__(256, 4) void attn_k(const unsigned short* __restrict__ qb,
    const unsigned short* __restrict__ kb, const unsigned short* __restrict__ vt,
    unsigned short* __restrict__ part, float* __restrict__ lsums){
  int blk = blockIdx.x;
  int bn = blk & 7;
  int sp = (blk >> 3) & (NSPLIT - 1);
  int qg = blk >> 6;                      // 0..31
  int t = threadIdx.x, w = t >> 6, l = t & 63;
  int lq = l & 31, hi = l >> 5;

  __shared__ unsigned short Klds[512 * KSTRIDE];   // 24 KB, row stride 48B

  {  // stage K chunk: 1024 16B-granules (2 per row), 4 per thread
    const unsigned short* ksrc = kb + ((size_t)bn*4096 + sp*512)*16;
    #pragma unroll
    for (int p = 0; p < 4; ++p){
      int g = p*256 + t;
      int r = g >> 1, h = g & 1;
      *(short8*)&Klds[r*KSTRIDE + h*8] = *(const short8*)(ksrc + (size_t)g*8);
    }
  }

  int qrow = qg*128 + w*32;
  short8 qf = *(const short8*)(qb + ((size_t)bn*4096 + qrow)*16 + (size_t)lq*16 + hi*8);

  int vrow = (lq < 16) ? lq : 16;         // clamp: rows 16.. = ones (lsum col)
  const unsigned short* vaddr = vt + ((size_t)bn*32 + vrow)*4096 + sp*512 + hi*8;

  f32x16 O0, O1, zero;
  #pragma unroll
  for (int r = 0; r < 16; ++r){ O0[r] = 0.f; O1[r] = 0.f; zero[r] = 0.f; }

  __syncthreads();                        // K staged; only barrier in the kernel

  auto packP = [&](const f32x16& pc, int h8) -> short8 {
    uint4v pw;
    pw[0] = pack2bf(pc[h8+0], pc[h8+1]);
    pw[1] = pack2bf(pc[h8+2], pc[h8+3]);
    pw[2] = pack2bf(pc[h8+4], pc[h8+5]);
    pw[3] = pack2bf(pc[h8+6], pc[h8+7]);
    return __builtin_bit_cast(short8, pw);
  };

  #pragma unroll
  for (int kt = 0; kt < NT; ++kt){
    // V loads (immediate offsets after unroll); unconditional, all 64 lanes
    const unsigned short* va = vaddr + kt*64;
    short8 v0 = *(const short8*)(va);
    short8 v1 = *(const short8*)(va + 16);
    short8 v2 = *(const short8*)(va + 32);
    short8 v3 = *(const short8*)(va + 48);
    // K ds_reads (immediate offsets, conflict-free stride)
    short8 kf0 = *(const short8*)&Klds[(kt*64 + lq)*KSTRIDE + hi*8];
    short8 kf1 = *(const short8*)&Klds[(kt*64 + 32 + lq)*KSTRIDE + hi*8];

    // S^T = K Q^T : lane holds S[kv][q=lq], kv = 64kt + 32c + (r&3)+8(r>>2)+4hi
    __builtin_amdgcn_s_setprio(1);
    f32x16 sA = __builtin_amdgcn_mfma_f32_32x32x16_bf16(kf0, qf, zero, 0, 0, 0);
    f32x16 sB = __builtin_amdgcn_mfma_f32_32x32x16_bf16(kf1, qf, zero, 0, 0, 0);
    __builtin_amdgcn_s_setprio(0);

    // max-free softmax: P = exp2(S) directly
    #pragma unroll
    for (int r = 0; r < 16; ++r) sA[r] = __builtin_amdgcn_exp2f(sA[r]);
    #pragma unroll
    for (int r = 0; r < 16; ++r) sB[r] = __builtin_amdgcn_exp2f(sB[r]);

    short8 paA0 = packP(sA, 0), paA1 = packP(sA, 8);
    short8 paB0 = packP(sB, 0), paB1 = packP(sB, 8);

    // PV: 4 K=16 steps; A-frag = lane's own 8 P-regs; split accumulators
    __builtin_amdgcn_s_setprio(1);
    O0 = __builtin_amdgcn_mfma_f32_32x32x16_bf16(paA0, v0, O0, 0, 0, 0);
    O1 = __builtin_amdgcn_mfma_f32_32x32x16_bf16(paA1, v1, O1, 0, 0, 0);
    O0 = __builtin_amdgcn_mfma_f32_32x32x16_bf16(paB0, v2, O0, 0, 0, 0);
    O1 = __builtin_amdgcn_mfma_f32_32x32x16_bf16(paB1, v3, O1, 0, 0, 0);
    __builtin_amdgcn_s_setprio(0);
  }

  #pragma unroll
  for (int r = 0; r < 16; ++r) O0[r] += O1[r];

  // D[row=q][col]: col=lq (d for lq<16, lsum at col 16); row=(r&3)+8(r>>2)+4hi
  unsigned short* Op = part + (((size_t)sp*8 + bn)*4096 + qrow)*16;
  size_t lbase = ((size_t)sp*8 + bn)*4096 + qrow;
  #pragma unroll
  for (int r = 0; r < 16; ++r){
    int qr = (r&3) + 8*(r>>2) + 4*hi;
    if (lq < 16) __builtin_nontemporal_store(f2bf(O0[r]), &Op[(size_t)qr*16 + lq]);
  }
  if (lq == 16){
    #pragma unroll
    for (int r = 0; r < 16; ++r){
      int qr = (r&3) + 8*(r>>2) + 4*hi;
      __builtin_nontemporal_store(O0[r], &lsums[lbase + qr]);
    }
  }
}

// ---------------- K4: split-combine (bf16 parts) + out 1x1 conv + bias + residual ----------------
// grid 512 = b(2) x s-tile(256 of 16)
__global__ __launch_bounds__(256) void oproj_k(const unsigned short* __restrict__ part,
    const float* __restrict__ lsums, const float* __restrict__ wo,
    const float* __restrict__ bo, const float* __restrict__ x,
    float* __restrict__ out){
  int b  = blockIdx.x >> 8;
  int s0 = (blockIdx.x & 255) * 16;
  __shared__ float W[64][68];
  __shared__ float A[16][68];     // [s_local][c]
  int t = threadIdx.x;
  for (int i = t; i < 1024; i += 256){
    int o = i >> 4, c4 = (i & 15) * 4;
    *(float4*)&W[o][c4] = ((const float4*)wo)[i];
  }
  {
    int sl = t & 15;
    int u  = t >> 4;
    int n = u >> 2, d4 = (u & 3) * 4;
    size_t row = ((size_t)b*4 + n)*4096 + s0 + sl;
    float L = 0.f;
    #pragma unroll
    for (int sp = 0; sp < NSPLIT; ++sp)
      L += __builtin_nontemporal_load(&lsums[(size_t)sp*32768 + row]);
    f32x4 acc = {0.f,0.f,0.f,0.f};
    #pragma unroll
    for (int sp = 0; sp < NSPLIT; ++sp){
      ushort4v u0 = *(const ushort4v*)(part + ((size_t)sp*32768 + row)*16 + d4);
      acc[0] += bf2f(u0[0]); acc[1] += bf2f(u0[1]);
      acc[2] += bf2f(u0[2]); acc[3] += bf2f(u0[3]);
    }
    float inv = 1.f / L;
    A[sl][n*16+d4+0] = acc[0]*inv; A[sl][n*16+d4+1] = acc[1]*inv;
    A[sl][n*16+d4+2] = acc[2]*inv; A[sl][n*16+d4+3] = acc[3]*inv;
  }
  __syncthreads();
  int sl = t & 15, grp = t >> 4;
  float acc[4] = {0.f,0.f,0.f,0.f};
  for (int c4 = 0; c4 < 16; ++c4){
    float4 a = *(const float4*)&A[sl][c4*4];
    #pragma unroll
    for (int j = 0; j < 4; ++j){
      float4 wv = *(const float4*)&W[grp + j*16][c4*4];
      acc[j] = fmaf(a.x, wv.x, fmaf(a.y, wv.y, fmaf(a.z, wv.z, fmaf(a.w, wv.w, acc[j]))));
    }
  }
  int s = s0 + sl;
  #pragma unroll
  for (int j = 0; j < 4; ++j){
    int o = grp + j*16;
    size_t idx = ((size_t)b*64 + o)*4096 + s;
    out[idx] = acc[j] + bo[o] + x[idx];
  }
}

extern "C" void kernel_launch(void* const* d_in, const int* in_sizes, int n_in,
                              void* d_out, int out_size, void* d_ws, size_t ws_size,
                              hipStream_t stream){
  const float* x   = (const float*)d_in[0];
  const float* gsc = (const float*)d_in[1];
  const float* gbi = (const float*)d_in[2];
  const float* wq  = (const float*)d_in[3];
  const float* wo  = (const float*)d_in[4];
  const float* bo  = (const float*)d_in[5];
  float* out = (float*)d_out;

  char* ws = (char*)d_ws;
  float* gp           = (float*)ws;                                 // 4 KB
  unsigned short* q   = (unsigned short*)(ws + 8192);               // 1 MB
  unsigned short* k   = (unsigned short*)(ws + 8192 + 1048576);     // 1 MB
  unsigned short* vt  = (unsigned short*)(ws + 8192 + 2097152);     // 2 MB (8bn x 32 x 4096)
  unsigned short* part= (unsigned short*)(ws + 8192 + 4194304);     // 8 MB bf16 (8sp)
  float* lsums        = (float*)(ws + 8192 + 4194304 + 8388608);    // 1 MB

  gn_partial_k<<<512,  256, 0, stream>>>(x, gp);
  qkv_k       <<<512,  256, 0, stream>>>(x, gp, gsc, gbi, wq, q, k, vt);
  attn_k      <<<2048, 256, 0, stream>>>(q, k, vt, part, lsums);
  oproj_k     <<<512,  256, 0, stream>>>(part, lsums, wo, bo, x, out);
}